// Round 1
// baseline (501.868 us; speedup 1.0000x reference)
//
#include <hip/hip_runtime.h>
#include <hip/hip_bf16.h>
#include <stdint.h>

#define CH 128

static __device__ __forceinline__ float4 ld4(const float* p) {
    return *reinterpret_cast<const float4*>(p);
}
static __device__ __forceinline__ float f4get(const float4& v, int i) {
    return i == 0 ? v.x : i == 1 ? v.y : i == 2 ? v.z : v.w;  // i is constant after unroll
}

// ---------------- edge histogram ----------------
__global__ void k_hist(const int* __restrict__ dst, int* __restrict__ deg, int nE) {
    int i = blockIdx.x * blockDim.x + threadIdx.x;
    int st = gridDim.x * blockDim.x;
    for (; i < nE; i += st) atomicAdd(&deg[dst[i]], 1);
}

// ---------------- per-1024-chunk sums for scan ----------------
__global__ void k_chunksum(const int* __restrict__ deg, int* __restrict__ bsum, int n) {
    __shared__ int sd[256];
    int b = blockIdx.x, t = threadIdx.x;
    int v = 0;
    for (int i = t; i < 1024; i += 256) {
        int idx = b * 1024 + i;
        if (idx < n) v += deg[idx];
    }
    sd[t] = v;
    __syncthreads();
    for (int o = 128; o > 0; o >>= 1) {
        if (t < o) sd[t] += sd[t + o];
        __syncthreads();
    }
    if (t == 0) bsum[b] = sd[0];
}

// ---------------- scan within chunk + write offsets/cursor ----------------
__global__ __launch_bounds__(1024) void k_scanwrite(const int* __restrict__ deg,
        const int* __restrict__ bsum, int* __restrict__ offs, int* __restrict__ cursor,
        int n, int nE) {
    __shared__ int sd[1024];
    int b = blockIdx.x, t = threadIdx.x;
    int boff = 0;
    for (int i = 0; i < b; ++i) boff += bsum[i];   // uniform scalar loads
    int gi = b * 1024 + t;
    int v = (gi < n) ? deg[gi] : 0;
    sd[t] = v;
    __syncthreads();
    for (int d = 1; d < 1024; d <<= 1) {
        int tv = (t >= d) ? sd[t - d] : 0;
        __syncthreads();
        sd[t] += tv;
        __syncthreads();
    }
    if (gi < n) {
        int ex = boff + sd[t] - v;   // exclusive prefix
        offs[gi] = ex;
        cursor[gi] = ex;
    }
    if (b == 0 && t == 0) offs[n] = nE;
}

// ---------------- scatter edges into CSR slots ----------------
__global__ void k_scatter(const int* __restrict__ src, const int* __restrict__ dst,
        int* __restrict__ cursor, int* __restrict__ csr, int nE) {
    int i = blockIdx.x * blockDim.x + threadIdx.x;
    int st = gridDim.x * blockDim.x;
    for (; i < nE; i += st) {
        int d = dst[i];
        int pos = atomicAdd(&cursor[d], 1);
        csr[pos] = src[i];
    }
}

// ---------------- GIN aggregate: h[i] = x[i] + sum_j x[src_j]  (one wave per node) ----
__global__ void k_aggregate(const float* __restrict__ x, const int* __restrict__ csr,
        const int* __restrict__ offs, float* __restrict__ h, int n) {
    int wid = (blockIdx.x * blockDim.x + threadIdx.x) >> 6;
    int lane = threadIdx.x & 63;
    int nw = (gridDim.x * blockDim.x) >> 6;
    int c = lane * 2;
    for (int node = wid; node < n; node += nw) {
        float2 a0 = *reinterpret_cast<const float2*>(&x[(size_t)node * CH + c]);
        float2 a1 = make_float2(0.f, 0.f);
        int s = offs[node], e = offs[node + 1];
        int i = s;
        for (; i + 1 < e; i += 2) {
            int s0 = csr[i], s1 = csr[i + 1];
            float2 v0 = *reinterpret_cast<const float2*>(&x[(size_t)s0 * CH + c]);
            float2 v1 = *reinterpret_cast<const float2*>(&x[(size_t)s1 * CH + c]);
            a0.x += v0.x; a0.y += v0.y;
            a1.x += v1.x; a1.y += v1.y;
        }
        if (i < e) {
            int s0 = csr[i];
            float2 v0 = *reinterpret_cast<const float2*>(&x[(size_t)s0 * CH + c]);
            a0.x += v0.x; a0.y += v0.y;
        }
        a0.x += a1.x; a0.y += a1.y;
        *reinterpret_cast<float2*>(&h[(size_t)node * CH + c]) = a0;
    }
}

// ---------------- 128-K GEMM + bias (+optional relu, +optional BN-stat partials) ----
// A,C may alias (in-place): each block only writes rows it owns, barrier before stores.
__global__ __launch_bounds__(256, 2) void k_gemm128(const float* A, const float* __restrict__ W,
        const float* __restrict__ bias, float* C, float* __restrict__ stats,
        int nrows, int doStats, int doRelu) {
    __shared__ float Wl[CH * CH];   // 64 KiB
    int tid = threadIdx.x;
    for (int i = tid; i < CH * CH / 4; i += 256)
        reinterpret_cast<float4*>(Wl)[i] = reinterpret_cast<const float4*>(W)[i];
    __syncthreads();

    int cg = tid & 15;   // 16 column-groups of 8 channels
    int rg = tid >> 4;   // 16 row-groups of 4 rows -> 64 rows per block-chunk
    float b8[8];
#pragma unroll
    for (int j = 0; j < 8; ++j) b8[j] = bias[cg * 8 + j];
    float ssum[8], ssq[8];
#pragma unroll
    for (int j = 0; j < 8; ++j) { ssum[j] = 0.f; ssq[j] = 0.f; }

    int nchunks = (nrows + 63) >> 6;
    for (int chunk = blockIdx.x; chunk < nchunks; chunk += gridDim.x) {
        int row0 = chunk * 64 + rg * 4;
        int r0 = min(row0 + 0, nrows - 1);
        int r1 = min(row0 + 1, nrows - 1);
        int r2 = min(row0 + 2, nrows - 1);
        int r3 = min(row0 + 3, nrows - 1);
        const float* A0 = A + (size_t)r0 * CH;
        const float* A1 = A + (size_t)r1 * CH;
        const float* A2 = A + (size_t)r2 * CH;
        const float* A3 = A + (size_t)r3 * CH;
        float acc[4][8];
#pragma unroll
        for (int r = 0; r < 4; ++r)
#pragma unroll
            for (int j = 0; j < 8; ++j) acc[r][j] = 0.f;

        for (int k = 0; k < CH; k += 4) {
            float4 a0 = ld4(A0 + k), a1 = ld4(A1 + k), a2 = ld4(A2 + k), a3 = ld4(A3 + k);
#pragma unroll
            for (int kk = 0; kk < 4; ++kk) {
                float4 w0 = ld4(&Wl[(k + kk) * CH + cg * 8]);
                float4 w1 = ld4(&Wl[(k + kk) * CH + cg * 8 + 4]);
                float e0 = f4get(a0, kk), e1 = f4get(a1, kk), e2 = f4get(a2, kk), e3 = f4get(a3, kk);
#define ROWFMA(r, e) \
                acc[r][0] += (e) * w0.x; acc[r][1] += (e) * w0.y; \
                acc[r][2] += (e) * w0.z; acc[r][3] += (e) * w0.w; \
                acc[r][4] += (e) * w1.x; acc[r][5] += (e) * w1.y; \
                acc[r][6] += (e) * w1.z; acc[r][7] += (e) * w1.w;
                ROWFMA(0, e0) ROWFMA(1, e1) ROWFMA(2, e2) ROWFMA(3, e3)
#undef ROWFMA
            }
        }

        __syncthreads();   // all reads of this chunk's rows complete before in-place stores
#pragma unroll
        for (int r = 0; r < 4; ++r) {
            int row = row0 + r;
            if (row < nrows) {
                float v[8];
#pragma unroll
                for (int j = 0; j < 8; ++j) {
                    float t = acc[r][j] + b8[j];
                    if (doRelu) t = fmaxf(t, 0.f);
                    v[j] = t;
                }
                if (doStats) {
#pragma unroll
                    for (int j = 0; j < 8; ++j) { ssum[j] += v[j]; ssq[j] += v[j] * v[j]; }
                }
                *reinterpret_cast<float4*>(&C[(size_t)row * CH + cg * 8]) =
                    make_float4(v[0], v[1], v[2], v[3]);
                *reinterpret_cast<float4*>(&C[(size_t)row * CH + cg * 8 + 4]) =
                    make_float4(v[4], v[5], v[6], v[7]);
            }
        }
    }

    if (doStats) {
#pragma unroll
        for (int j = 0; j < 8; ++j) {
            ssum[j] += __shfl_xor(ssum[j], 16, 64); ssum[j] += __shfl_xor(ssum[j], 32, 64);
            ssq[j]  += __shfl_xor(ssq[j], 16, 64);  ssq[j]  += __shfl_xor(ssq[j], 32, 64);
        }
        __syncthreads();
        float* red = Wl;   // reuse W LDS as reduce scratch (W no longer needed)
        int wv = tid >> 6, lane = tid & 63;
        if (lane < 16) {
#pragma unroll
            for (int j = 0; j < 8; ++j) {
                red[wv * 128 + lane * 8 + j] = ssum[j];
                red[512 + wv * 128 + lane * 8 + j] = ssq[j];
            }
        }
        __syncthreads();
        if (tid < 128) {
            float s = 0.f, q = 0.f;
#pragma unroll
            for (int w = 0; w < 4; ++w) { s += red[w * 128 + tid]; q += red[512 + w * 128 + tid]; }
            atomicAdd(&stats[tid], s);
            atomicAdd(&stats[128 + tid], q);
        }
    }
}

// ---------------- BN finalize: per-channel scale/shift ----------------
__global__ void k_bnfin(const float* __restrict__ stats, const float* __restrict__ gamma,
        const float* __restrict__ beta, float* __restrict__ scsh, float invN) {
    int c = threadIdx.x;
    if (c < CH) {
        float mean = stats[c] * invN;
        float var = stats[CH + c] * invN - mean * mean;   // biased, as in ref
        float sc = gamma[c] * rsqrtf(var + 1e-5f);
        scsh[c] = sc;
        scsh[CH + c] = beta[c] - mean * sc;
    }
}

// ---------------- normalize + relu, in place ----------------
__global__ void k_bnrelu(float* h, const float* __restrict__ scsh, int n4) {
    int i = blockIdx.x * blockDim.x + threadIdx.x;
    int st = gridDim.x * blockDim.x;
    for (; i < n4; i += st) {
        int c0 = (i & 31) * 4;   // 32 float4 per 128-ch row
        float4 v = reinterpret_cast<float4*>(h)[i];
        float4 sc = *reinterpret_cast<const float4*>(&scsh[c0]);
        float4 sh = *reinterpret_cast<const float4*>(&scsh[CH + c0]);
        v.x = fmaxf(fmaf(v.x, sc.x, sh.x), 0.f);
        v.y = fmaxf(fmaf(v.y, sc.y, sh.y), 0.f);
        v.z = fmaxf(fmaf(v.z, sc.z, sh.z), 0.f);
        v.w = fmaxf(fmaf(v.w, sc.w, sh.w), 0.f);
        reinterpret_cast<float4*>(h)[i] = v;
    }
}

extern "C" void kernel_launch(void* const* d_in, const int* in_sizes, int n_in,
                              void* d_out, int out_size, void* d_ws, size_t ws_size,
                              hipStream_t stream) {
    const float* x     = (const float*)d_in[0];
    const int*   ei    = (const int*)d_in[1];
    const float* W1    = (const float*)d_in[2];
    const float* b1    = (const float*)d_in[3];
    const float* gamma = (const float*)d_in[4];
    const float* beta  = (const float*)d_in[5];
    const float* W2    = (const float*)d_in[6];
    const float* b2    = (const float*)d_in[7];
    float* out = (float*)d_out;

    const int N = in_sizes[0] / CH;   // 100000
    const int E = in_sizes[1] / 2;    // 1600000
    const int* esrc = ei;
    const int* edst = ei + E;

    // workspace carve-out (~7.8 MB total)
    char* w = (char*)d_ws;
    auto take = [&](size_t bytes) {
        char* p = w;
        w += (bytes + 255) & ~(size_t)255;
        return p;
    };
    int*   csr    = (int*)take((size_t)E * 4);
    int*   deg    = (int*)take((size_t)N * 4);
    int*   offs   = (int*)take((size_t)(N + 1) * 4);
    int*   cursor = (int*)take((size_t)N * 4);
    int*   bsum   = (int*)take(1024 * 4);
    float* stats  = (float*)take(256 * 4);
    float* scsh   = (float*)take(256 * 4);

    float* h = out;   // d_out doubles as the [N][128] fp32 intermediate

    hipMemsetAsync(deg, 0, (size_t)N * 4, stream);
    hipMemsetAsync(stats, 0, 256 * 4, stream);

    int nb = (N + 1023) / 1024;   // 98
    k_hist<<<2048, 256, 0, stream>>>(edst, deg, E);
    k_chunksum<<<nb, 256, 0, stream>>>(deg, bsum, N);
    k_scanwrite<<<nb, 1024, 0, stream>>>(deg, bsum, offs, cursor, N, E);
    k_scatter<<<2048, 256, 0, stream>>>(esrc, edst, cursor, csr, E);
    k_aggregate<<<4096, 256, 0, stream>>>(x, csr, offs, h, N);
    k_gemm128<<<512, 256, 0, stream>>>(h, W1, b1, h, stats, N, 1, 0);
    k_bnfin<<<1, 128, 0, stream>>>(stats, gamma, beta, scsh, 1.0f / (float)N);
    k_bnrelu<<<2048, 256, 0, stream>>>(h, scsh, N * CH / 4);
    k_gemm128<<<512, 256, 0, stream>>>(h, W2, b2, out, nullptr, N, 0, 1);
}

// Round 2
// 455.118 us; speedup vs baseline: 1.1027x; 1.1027x over previous
//
#include <hip/hip_runtime.h>
#include <hip/hip_bf16.h>
#include <hip/hip_fp16.h>
#include <stdint.h>

#define CH 128

static __device__ __forceinline__ float4 ld4(const float* p) {
    return *reinterpret_cast<const float4*>(p);
}
static __device__ __forceinline__ float f4get(const float4& v, int i) {
    return i == 0 ? v.x : i == 1 ? v.y : i == 2 ? v.z : v.w;  // i constant after unroll
}

// ---------------- edge histogram ----------------
__global__ void k_hist(const int* __restrict__ dst, int* __restrict__ deg, int nE) {
    int i = blockIdx.x * blockDim.x + threadIdx.x;
    int st = gridDim.x * blockDim.x;
    for (; i < nE; i += st) atomicAdd(&deg[dst[i]], 1);
}

// ---------------- per-1024-chunk sums for scan ----------------
__global__ void k_chunksum(const int* __restrict__ deg, int* __restrict__ bsum, int n) {
    __shared__ int sd[256];
    int b = blockIdx.x, t = threadIdx.x;
    int v = 0;
    for (int i = t; i < 1024; i += 256) {
        int idx = b * 1024 + i;
        if (idx < n) v += deg[idx];
    }
    sd[t] = v;
    __syncthreads();
    for (int o = 128; o > 0; o >>= 1) {
        if (t < o) sd[t] += sd[t + o];
        __syncthreads();
    }
    if (t == 0) bsum[b] = sd[0];
}

// ---------------- scan within chunk + write offsets/cursor ----------------
__global__ __launch_bounds__(1024) void k_scanwrite(const int* __restrict__ deg,
        const int* __restrict__ bsum, int* __restrict__ offs, int* __restrict__ cursor,
        int n, int nE) {
    __shared__ int sd[1024];
    int b = blockIdx.x, t = threadIdx.x;
    int boff = 0;
    for (int i = 0; i < b; ++i) boff += bsum[i];
    int gi = b * 1024 + t;
    int v = (gi < n) ? deg[gi] : 0;
    sd[t] = v;
    __syncthreads();
    for (int d = 1; d < 1024; d <<= 1) {
        int tv = (t >= d) ? sd[t - d] : 0;
        __syncthreads();
        sd[t] += tv;
        __syncthreads();
    }
    if (gi < n) {
        int ex = boff + sd[t] - v;
        offs[gi] = ex;
        cursor[gi] = ex;
    }
    if (b == 0 && t == 0) offs[n] = nE;
}

// ---------------- scatter edges into CSR slots ----------------
__global__ void k_scatter(const int* __restrict__ src, const int* __restrict__ dst,
        int* __restrict__ cursor, int* __restrict__ csr, int nE) {
    int i = blockIdx.x * blockDim.x + threadIdx.x;
    int st = gridDim.x * blockDim.x;
    for (; i < nE; i += st) {
        int d = dst[i];
        int pos = atomicAdd(&cursor[d], 1);
        csr[pos] = src[i];
    }
}

// ---------------- x -> fp16 copy (halves gather bytes) ----------------
__global__ void k_tofp16(const float* __restrict__ x, uint32_t* __restrict__ xh, int n8) {
    int i = blockIdx.x * blockDim.x + threadIdx.x;
    int st = gridDim.x * blockDim.x;
    for (; i < n8; i += st) {
        float4 v0 = ld4(x + (size_t)i * 8);
        float4 v1 = ld4(x + (size_t)i * 8 + 4);
        __half2 h0 = __floats2half2_rn(v0.x, v0.y);
        __half2 h1 = __floats2half2_rn(v0.z, v0.w);
        __half2 h2 = __floats2half2_rn(v1.x, v1.y);
        __half2 h3 = __floats2half2_rn(v1.z, v1.w);
        uint4 o;
        o.x = *reinterpret_cast<unsigned*>(&h0);
        o.y = *reinterpret_cast<unsigned*>(&h1);
        o.z = *reinterpret_cast<unsigned*>(&h2);
        o.w = *reinterpret_cast<unsigned*>(&h3);
        reinterpret_cast<uint4*>(xh)[i] = o;
    }
}

// ---------------- GIN aggregate via fp16 gather: h[i] = x[i] + sum_j xh[src_j] ----
__global__ void k_aggregate_h(const float* __restrict__ x, const __half2* __restrict__ xh,
        const int* __restrict__ csr, const int* __restrict__ offs, float* __restrict__ h, int n) {
    int wid = (blockIdx.x * blockDim.x + threadIdx.x) >> 6;
    int lane = threadIdx.x & 63;
    int nw = (gridDim.x * blockDim.x) >> 6;
    for (int node = wid; node < n; node += nw) {
        float2 a0 = *reinterpret_cast<const float2*>(&x[(size_t)node * CH + lane * 2]);
        float2 a1 = make_float2(0.f, 0.f), a2 = make_float2(0.f, 0.f), a3 = make_float2(0.f, 0.f);
        int s = offs[node], e = offs[node + 1];
        int i = s;
        for (; i + 3 < e; i += 4) {
            int s0 = csr[i], s1 = csr[i + 1], s2 = csr[i + 2], s3 = csr[i + 3];
            float2 v0 = __half22float2(xh[(size_t)s0 * 64 + lane]);
            float2 v1 = __half22float2(xh[(size_t)s1 * 64 + lane]);
            float2 v2 = __half22float2(xh[(size_t)s2 * 64 + lane]);
            float2 v3 = __half22float2(xh[(size_t)s3 * 64 + lane]);
            a0.x += v0.x; a0.y += v0.y;
            a1.x += v1.x; a1.y += v1.y;
            a2.x += v2.x; a2.y += v2.y;
            a3.x += v3.x; a3.y += v3.y;
        }
        for (; i < e; ++i) {
            float2 v0 = __half22float2(xh[(size_t)csr[i] * 64 + lane]);
            a0.x += v0.x; a0.y += v0.y;
        }
        a0.x += a1.x + a2.x + a3.x;
        a0.y += a1.y + a2.y + a3.y;
        *reinterpret_cast<float2*>(&h[(size_t)node * CH + lane * 2]) = a0;
    }
}

// ---------------- fp32 fallback aggregate (if ws too small for fp16 copy) ----------
__global__ void k_aggregate(const float* __restrict__ x, const int* __restrict__ csr,
        const int* __restrict__ offs, float* __restrict__ h, int n) {
    int wid = (blockIdx.x * blockDim.x + threadIdx.x) >> 6;
    int lane = threadIdx.x & 63;
    int nw = (gridDim.x * blockDim.x) >> 6;
    int c = lane * 2;
    for (int node = wid; node < n; node += nw) {
        float2 a0 = *reinterpret_cast<const float2*>(&x[(size_t)node * CH + c]);
        float2 a1 = make_float2(0.f, 0.f);
        int s = offs[node], e = offs[node + 1];
        int i = s;
        for (; i + 1 < e; i += 2) {
            int s0 = csr[i], s1 = csr[i + 1];
            float2 v0 = *reinterpret_cast<const float2*>(&x[(size_t)s0 * CH + c]);
            float2 v1 = *reinterpret_cast<const float2*>(&x[(size_t)s1 * CH + c]);
            a0.x += v0.x; a0.y += v0.y;
            a1.x += v1.x; a1.y += v1.y;
        }
        if (i < e) {
            float2 v0 = *reinterpret_cast<const float2*>(&x[(size_t)csr[i] * CH + c]);
            a0.x += v0.x; a0.y += v0.y;
        }
        a0.x += a1.x; a0.y += a1.y;
        *reinterpret_cast<float2*>(&h[(size_t)node * CH + c]) = a0;
    }
}

// ---------------- 128-K GEMM + bias; optional BN-on-load, relu, BN-stat partials ----
// 8 rows x 8 cols per thread -> 2 ds_read_b128 feed 64 FMAs.
// A,C may alias: block only writes rows it owns, barrier between k-loop and stores.
__global__ __launch_bounds__(256, 2) void k_gemm128(const float* A, const float* __restrict__ W,
        const float* __restrict__ bias, float* C, float* __restrict__ stats,
        const float* __restrict__ bnsc,   // if nonnull: a = relu(a*sc[k] + sh[k]) on load
        int nrows, int doStats, int doRelu) {
    __shared__ float Wl[CH * CH];   // 64 KiB
    int tid = threadIdx.x;
    for (int i = tid; i < CH * CH / 4; i += 256)
        reinterpret_cast<float4*>(Wl)[i] = reinterpret_cast<const float4*>(W)[i];
    __syncthreads();

    int cg = tid & 15;   // 16 column-groups of 8 channels
    int rg = tid >> 4;   // 16 row-groups of 8 rows -> 128 rows per chunk
    float b8[8];
#pragma unroll
    for (int j = 0; j < 8; ++j) b8[j] = bias[cg * 8 + j];
    float ssum[8], ssq[8];
#pragma unroll
    for (int j = 0; j < 8; ++j) { ssum[j] = 0.f; ssq[j] = 0.f; }

    int nchunks = (nrows + 127) >> 7;
    for (int chunk = blockIdx.x; chunk < nchunks; chunk += gridDim.x) {
        int row0 = chunk * 128 + rg * 8;
        const float* Ap[8];
#pragma unroll
        for (int r = 0; r < 8; ++r)
            Ap[r] = A + (size_t)min(row0 + r, nrows - 1) * CH;

        float acc[8][8];
#pragma unroll
        for (int r = 0; r < 8; ++r)
#pragma unroll
            for (int j = 0; j < 8; ++j) acc[r][j] = 0.f;

        for (int k = 0; k < CH; k += 4) {
            float4 a[8];
#pragma unroll
            for (int r = 0; r < 8; ++r) a[r] = ld4(Ap[r] + k);
            if (bnsc) {
                float4 sc = ld4(bnsc + k), sh = ld4(bnsc + CH + k);
#pragma unroll
                for (int r = 0; r < 8; ++r) {
                    a[r].x = fmaxf(fmaf(a[r].x, sc.x, sh.x), 0.f);
                    a[r].y = fmaxf(fmaf(a[r].y, sc.y, sh.y), 0.f);
                    a[r].z = fmaxf(fmaf(a[r].z, sc.z, sh.z), 0.f);
                    a[r].w = fmaxf(fmaf(a[r].w, sc.w, sh.w), 0.f);
                }
            }
#pragma unroll
            for (int kk = 0; kk < 4; ++kk) {
                float4 w0 = ld4(&Wl[(k + kk) * CH + cg * 8]);
                float4 w1 = ld4(&Wl[(k + kk) * CH + cg * 8 + 4]);
#pragma unroll
                for (int r = 0; r < 8; ++r) {
                    float e = f4get(a[r], kk);
                    acc[r][0] += e * w0.x; acc[r][1] += e * w0.y;
                    acc[r][2] += e * w0.z; acc[r][3] += e * w0.w;
                    acc[r][4] += e * w1.x; acc[r][5] += e * w1.y;
                    acc[r][6] += e * w1.z; acc[r][7] += e * w1.w;
                }
            }
        }

        __syncthreads();   // all in-place reads of this chunk complete before stores
#pragma unroll
        for (int r = 0; r < 8; ++r) {
            int row = row0 + r;
            if (row < nrows) {
                float v[8];
#pragma unroll
                for (int j = 0; j < 8; ++j) {
                    float t = acc[r][j] + b8[j];
                    if (doRelu) t = fmaxf(t, 0.f);
                    v[j] = t;
                }
                if (doStats) {
#pragma unroll
                    for (int j = 0; j < 8; ++j) { ssum[j] += v[j]; ssq[j] += v[j] * v[j]; }
                }
                *reinterpret_cast<float4*>(&C[(size_t)row * CH + cg * 8]) =
                    make_float4(v[0], v[1], v[2], v[3]);
                *reinterpret_cast<float4*>(&C[(size_t)row * CH + cg * 8 + 4]) =
                    make_float4(v[4], v[5], v[6], v[7]);
            }
        }
    }

    if (doStats) {
#pragma unroll
        for (int j = 0; j < 8; ++j) {
            ssum[j] += __shfl_xor(ssum[j], 16, 64); ssum[j] += __shfl_xor(ssum[j], 32, 64);
            ssq[j]  += __shfl_xor(ssq[j], 16, 64);  ssq[j]  += __shfl_xor(ssq[j], 32, 64);
        }
        __syncthreads();
        float* red = Wl;   // reuse W LDS (W no longer needed)
        int wv = tid >> 6, lane = tid & 63;
        if (lane < 16) {
#pragma unroll
            for (int j = 0; j < 8; ++j) {
                red[wv * 128 + lane * 8 + j] = ssum[j];
                red[512 + wv * 128 + lane * 8 + j] = ssq[j];
            }
        }
        __syncthreads();
        if (tid < 128) {
            float s = 0.f, q = 0.f;
#pragma unroll
            for (int w = 0; w < 4; ++w) { s += red[w * 128 + tid]; q += red[512 + w * 128 + tid]; }
            atomicAdd(&stats[tid], s);
            atomicAdd(&stats[128 + tid], q);
        }
    }
}

// ---------------- BN finalize: per-channel scale/shift ----------------
__global__ void k_bnfin(const float* __restrict__ stats, const float* __restrict__ gamma,
        const float* __restrict__ beta, float* __restrict__ scsh, float invN) {
    int c = threadIdx.x;
    if (c < CH) {
        float mean = stats[c] * invN;
        float var = stats[CH + c] * invN - mean * mean;   // biased, as in ref
        float sc = gamma[c] * rsqrtf(var + 1e-5f);
        scsh[c] = sc;
        scsh[CH + c] = beta[c] - mean * sc;
    }
}

extern "C" void kernel_launch(void* const* d_in, const int* in_sizes, int n_in,
                              void* d_out, int out_size, void* d_ws, size_t ws_size,
                              hipStream_t stream) {
    const float* x     = (const float*)d_in[0];
    const int*   ei    = (const int*)d_in[1];
    const float* W1    = (const float*)d_in[2];
    const float* b1    = (const float*)d_in[3];
    const float* gamma = (const float*)d_in[4];
    const float* beta  = (const float*)d_in[5];
    const float* W2    = (const float*)d_in[6];
    const float* b2    = (const float*)d_in[7];
    float* out = (float*)d_out;

    const int N = in_sizes[0] / CH;   // 100000
    const int E = in_sizes[1] / 2;    // 1600000
    const int* esrc = ei;
    const int* edst = ei + E;

    char* w = (char*)d_ws;
    auto take = [&](size_t bytes) {
        char* p = w;
        w += (bytes + 255) & ~(size_t)255;
        return p;
    };
    int*      csr    = (int*)take((size_t)E * 4);
    int*      deg    = (int*)take((size_t)N * 4);
    int*      offs   = (int*)take((size_t)(N + 1) * 4);
    int*      cursor = (int*)take((size_t)N * 4);
    int*      bsum   = (int*)take(1024 * 4);
    float*    stats  = (float*)take(256 * 4);
    float*    scsh   = (float*)take(256 * 4);
    uint32_t* xh     = (uint32_t*)take((size_t)N * CH * 2);   // fp16 copy of x
    bool useFp16 = ((size_t)(w - (char*)d_ws) <= ws_size);

    float* h = out;   // d_out doubles as the [N][128] fp32 intermediate

    hipMemsetAsync(deg, 0, (size_t)N * 4, stream);
    hipMemsetAsync(stats, 0, 256 * 4, stream);

    int nb = (N + 1023) / 1024;
    k_hist<<<2048, 256, 0, stream>>>(edst, deg, E);
    k_chunksum<<<nb, 256, 0, stream>>>(deg, bsum, N);
    k_scanwrite<<<nb, 1024, 0, stream>>>(deg, bsum, offs, cursor, N, E);
    k_scatter<<<2048, 256, 0, stream>>>(esrc, edst, cursor, csr, E);
    if (useFp16) {
        k_tofp16<<<2048, 256, 0, stream>>>(x, xh, N * CH / 8);
        k_aggregate_h<<<4096, 256, 0, stream>>>(x, (const __half2*)xh, csr, offs, h, N);
    } else {
        k_aggregate<<<4096, 256, 0, stream>>>(x, csr, offs, h, N);
    }
    k_gemm128<<<512, 256, 0, stream>>>(h, W1, b1, h, stats, nullptr, N, 1, 0);
    k_bnfin<<<1, 128, 0, stream>>>(stats, gamma, beta, scsh, 1.0f / (float)N);
    k_gemm128<<<512, 256, 0, stream>>>(h, W2, b2, out, nullptr, scsh, N, 0, 1);
}

// Round 3
// 416.214 us; speedup vs baseline: 1.2058x; 1.0935x over previous
//
#include <hip/hip_runtime.h>
#include <hip/hip_bf16.h>
#include <hip/hip_fp16.h>
#include <stdint.h>

#define CH 128

static __device__ __forceinline__ float4 ld4(const float* p) {
    return *reinterpret_cast<const float4*>(p);
}
static __device__ __forceinline__ float f4get(const float4& v, int i) {
    return i == 0 ? v.x : i == 1 ? v.y : i == 2 ? v.z : v.w;  // i constant after unroll
}

// ---------------- edge histogram ----------------
__global__ void k_hist(const int* __restrict__ dst, int* __restrict__ deg, int nE) {
    int i = blockIdx.x * blockDim.x + threadIdx.x;
    int st = gridDim.x * blockDim.x;
    for (; i < nE; i += st) atomicAdd(&deg[dst[i]], 1);
}

// ---------------- per-1024-chunk sums for scan ----------------
__global__ void k_chunksum(const int* __restrict__ deg, int* __restrict__ bsum, int n) {
    __shared__ int sd[256];
    int b = blockIdx.x, t = threadIdx.x;
    int v = 0;
    for (int i = t; i < 1024; i += 256) {
        int idx = b * 1024 + i;
        if (idx < n) v += deg[idx];
    }
    sd[t] = v;
    __syncthreads();
    for (int o = 128; o > 0; o >>= 1) {
        if (t < o) sd[t] += sd[t + o];
        __syncthreads();
    }
    if (t == 0) bsum[b] = sd[0];
}

// ---------------- scan within chunk + write offsets/cursor ----------------
__global__ __launch_bounds__(1024) void k_scanwrite(const int* __restrict__ deg,
        const int* __restrict__ bsum, int* __restrict__ offs, int* __restrict__ cursor,
        int n, int nE) {
    __shared__ int sd[1024];
    int b = blockIdx.x, t = threadIdx.x;
    int boff = 0;
    for (int i = 0; i < b; ++i) boff += bsum[i];
    int gi = b * 1024 + t;
    int v = (gi < n) ? deg[gi] : 0;
    sd[t] = v;
    __syncthreads();
    for (int d = 1; d < 1024; d <<= 1) {
        int tv = (t >= d) ? sd[t - d] : 0;
        __syncthreads();
        sd[t] += tv;
        __syncthreads();
    }
    if (gi < n) {
        int ex = boff + sd[t] - v;
        offs[gi] = ex;
        cursor[gi] = ex;
    }
    if (b == 0 && t == 0) offs[n] = nE;
}

// ---------------- scatter edges into CSR slots, L2-localized by dst-range passes ----
// Pass p handles only edges with dst in [p*rangeSize, (p+1)*rangeSize): all random
// csr/cursor traffic stays in a ~400KB/25KB L2-resident window; HBM sees only the
// final full-line writeback. Each block's edge chunk is L1-resident across passes.
__global__ void k_scatter(const int* __restrict__ src, const int* __restrict__ dst,
        int* __restrict__ cursor, int* __restrict__ csr, int nE, int nPass, int rangeSize) {
    int base = blockIdx.x * blockDim.x + threadIdx.x;
    int st = gridDim.x * blockDim.x;
    for (int p = 0; p < nPass; ++p) {
        int lo = p * rangeSize;
        int hi = lo + rangeSize;
        for (int i = base; i < nE; i += st) {
            int d = dst[i];
            if (d >= lo && d < hi) {
                int pos = atomicAdd(&cursor[d], 1);
                csr[pos] = src[i];
            }
        }
    }
}

// ---------------- x -> fp16 copy (halves gather bytes) ----------------
__global__ void k_tofp16(const float* __restrict__ x, uint32_t* __restrict__ xh, int n8) {
    int i = blockIdx.x * blockDim.x + threadIdx.x;
    int st = gridDim.x * blockDim.x;
    for (; i < n8; i += st) {
        float4 v0 = ld4(x + (size_t)i * 8);
        float4 v1 = ld4(x + (size_t)i * 8 + 4);
        __half2 h0 = __floats2half2_rn(v0.x, v0.y);
        __half2 h1 = __floats2half2_rn(v0.z, v0.w);
        __half2 h2 = __floats2half2_rn(v1.x, v1.y);
        __half2 h3 = __floats2half2_rn(v1.z, v1.w);
        uint4 o;
        o.x = *reinterpret_cast<unsigned*>(&h0);
        o.y = *reinterpret_cast<unsigned*>(&h1);
        o.z = *reinterpret_cast<unsigned*>(&h2);
        o.w = *reinterpret_cast<unsigned*>(&h3);
        reinterpret_cast<uint4*>(xh)[i] = o;
    }
}

// ---------------- GIN aggregate via fp16 gather: h[i] = x[i] + sum_j xh[src_j] ----
__global__ void k_aggregate_h(const float* __restrict__ x, const __half2* __restrict__ xh,
        const int* __restrict__ csr, const int* __restrict__ offs, float* __restrict__ h, int n) {
    int wid = (blockIdx.x * blockDim.x + threadIdx.x) >> 6;
    int lane = threadIdx.x & 63;
    int nw = (gridDim.x * blockDim.x) >> 6;
    for (int node = wid; node < n; node += nw) {
        float2 a0 = *reinterpret_cast<const float2*>(&x[(size_t)node * CH + lane * 2]);
        float2 a1 = make_float2(0.f, 0.f), a2 = make_float2(0.f, 0.f), a3 = make_float2(0.f, 0.f);
        int s = offs[node], e = offs[node + 1];
        int i = s;
        for (; i + 3 < e; i += 4) {
            int s0 = csr[i], s1 = csr[i + 1], s2 = csr[i + 2], s3 = csr[i + 3];
            float2 v0 = __half22float2(xh[(size_t)s0 * 64 + lane]);
            float2 v1 = __half22float2(xh[(size_t)s1 * 64 + lane]);
            float2 v2 = __half22float2(xh[(size_t)s2 * 64 + lane]);
            float2 v3 = __half22float2(xh[(size_t)s3 * 64 + lane]);
            a0.x += v0.x; a0.y += v0.y;
            a1.x += v1.x; a1.y += v1.y;
            a2.x += v2.x; a2.y += v2.y;
            a3.x += v3.x; a3.y += v3.y;
        }
        for (; i < e; ++i) {
            float2 v0 = __half22float2(xh[(size_t)csr[i] * 64 + lane]);
            a0.x += v0.x; a0.y += v0.y;
        }
        a0.x += a1.x + a2.x + a3.x;
        a0.y += a1.y + a2.y + a3.y;
        *reinterpret_cast<float2*>(&h[(size_t)node * CH + lane * 2]) = a0;
    }
}

// ---------------- fp32 fallback aggregate (if ws too small for fp16 copy) ----------
__global__ void k_aggregate(const float* __restrict__ x, const int* __restrict__ csr,
        const int* __restrict__ offs, float* __restrict__ h, int n) {
    int wid = (blockIdx.x * blockDim.x + threadIdx.x) >> 6;
    int lane = threadIdx.x & 63;
    int nw = (gridDim.x * blockDim.x) >> 6;
    int c = lane * 2;
    for (int node = wid; node < n; node += nw) {
        float2 a0 = *reinterpret_cast<const float2*>(&x[(size_t)node * CH + c]);
        float2 a1 = make_float2(0.f, 0.f);
        int s = offs[node], e = offs[node + 1];
        int i = s;
        for (; i + 1 < e; i += 2) {
            int s0 = csr[i], s1 = csr[i + 1];
            float2 v0 = *reinterpret_cast<const float2*>(&x[(size_t)s0 * CH + c]);
            float2 v1 = *reinterpret_cast<const float2*>(&x[(size_t)s1 * CH + c]);
            a0.x += v0.x; a0.y += v0.y;
            a1.x += v1.x; a1.y += v1.y;
        }
        if (i < e) {
            float2 v0 = *reinterpret_cast<const float2*>(&x[(size_t)csr[i] * CH + c]);
            a0.x += v0.x; a0.y += v0.y;
        }
        a0.x += a1.x; a0.y += a1.y;
        *reinterpret_cast<float2*>(&h[(size_t)node * CH + c]) = a0;
    }
}

// ---------------- 128-K GEMM + bias; optional BN-on-load, relu, BN-stat partials ----
// 8 rows x 8 cols per thread -> 2 ds_read_b128 feed 64 FMAs.
// A,C may alias: block only writes rows it owns, barrier between k-loop and stores.
__global__ __launch_bounds__(256, 2) void k_gemm128(const float* A, const float* __restrict__ W,
        const float* __restrict__ bias, float* C, float* __restrict__ stats,
        const float* __restrict__ bnsc,   // if nonnull: a = relu(a*sc[k] + sh[k]) on load
        int nrows, int doStats, int doRelu) {
    __shared__ float Wl[CH * CH];   // 64 KiB
    int tid = threadIdx.x;
    for (int i = tid; i < CH * CH / 4; i += 256)
        reinterpret_cast<float4*>(Wl)[i] = reinterpret_cast<const float4*>(W)[i];
    __syncthreads();

    int cg = tid & 15;   // 16 column-groups of 8 channels
    int rg = tid >> 4;   // 16 row-groups of 8 rows -> 128 rows per chunk
    float b8[8];
#pragma unroll
    for (int j = 0; j < 8; ++j) b8[j] = bias[cg * 8 + j];
    float ssum[8], ssq[8];
#pragma unroll
    for (int j = 0; j < 8; ++j) { ssum[j] = 0.f; ssq[j] = 0.f; }

    int nchunks = (nrows + 127) >> 7;
    for (int chunk = blockIdx.x; chunk < nchunks; chunk += gridDim.x) {
        int row0 = chunk * 128 + rg * 8;
        const float* Ap[8];
#pragma unroll
        for (int r = 0; r < 8; ++r)
            Ap[r] = A + (size_t)min(row0 + r, nrows - 1) * CH;

        float acc[8][8];
#pragma unroll
        for (int r = 0; r < 8; ++r)
#pragma unroll
            for (int j = 0; j < 8; ++j) acc[r][j] = 0.f;

        for (int k = 0; k < CH; k += 4) {
            float4 a[8];
#pragma unroll
            for (int r = 0; r < 8; ++r) a[r] = ld4(Ap[r] + k);
            if (bnsc) {
                float4 sc = ld4(bnsc + k), sh = ld4(bnsc + CH + k);
#pragma unroll
                for (int r = 0; r < 8; ++r) {
                    a[r].x = fmaxf(fmaf(a[r].x, sc.x, sh.x), 0.f);
                    a[r].y = fmaxf(fmaf(a[r].y, sc.y, sh.y), 0.f);
                    a[r].z = fmaxf(fmaf(a[r].z, sc.z, sh.z), 0.f);
                    a[r].w = fmaxf(fmaf(a[r].w, sc.w, sh.w), 0.f);
                }
            }
#pragma unroll
            for (int kk = 0; kk < 4; ++kk) {
                float4 w0 = ld4(&Wl[(k + kk) * CH + cg * 8]);
                float4 w1 = ld4(&Wl[(k + kk) * CH + cg * 8 + 4]);
#pragma unroll
                for (int r = 0; r < 8; ++r) {
                    float e = f4get(a[r], kk);
                    acc[r][0] += e * w0.x; acc[r][1] += e * w0.y;
                    acc[r][2] += e * w0.z; acc[r][3] += e * w0.w;
                    acc[r][4] += e * w1.x; acc[r][5] += e * w1.y;
                    acc[r][6] += e * w1.z; acc[r][7] += e * w1.w;
                }
            }
        }

        __syncthreads();   // all in-place reads of this chunk complete before stores
#pragma unroll
        for (int r = 0; r < 8; ++r) {
            int row = row0 + r;
            if (row < nrows) {
                float v[8];
#pragma unroll
                for (int j = 0; j < 8; ++j) {
                    float t = acc[r][j] + b8[j];
                    if (doRelu) t = fmaxf(t, 0.f);
                    v[j] = t;
                }
                if (doStats) {
#pragma unroll
                    for (int j = 0; j < 8; ++j) { ssum[j] += v[j]; ssq[j] += v[j] * v[j]; }
                }
                *reinterpret_cast<float4*>(&C[(size_t)row * CH + cg * 8]) =
                    make_float4(v[0], v[1], v[2], v[3]);
                *reinterpret_cast<float4*>(&C[(size_t)row * CH + cg * 8 + 4]) =
                    make_float4(v[4], v[5], v[6], v[7]);
            }
        }
    }

    if (doStats) {
#pragma unroll
        for (int j = 0; j < 8; ++j) {
            ssum[j] += __shfl_xor(ssum[j], 16, 64); ssum[j] += __shfl_xor(ssum[j], 32, 64);
            ssq[j]  += __shfl_xor(ssq[j], 16, 64);  ssq[j]  += __shfl_xor(ssq[j], 32, 64);
        }
        __syncthreads();
        float* red = Wl;   // reuse W LDS (W no longer needed)
        int wv = tid >> 6, lane = tid & 63;
        if (lane < 16) {
#pragma unroll
            for (int j = 0; j < 8; ++j) {
                red[wv * 128 + lane * 8 + j] = ssum[j];
                red[512 + wv * 128 + lane * 8 + j] = ssq[j];
            }
        }
        __syncthreads();
        if (tid < 128) {
            float s = 0.f, q = 0.f;
#pragma unroll
            for (int w = 0; w < 4; ++w) { s += red[w * 128 + tid]; q += red[512 + w * 128 + tid]; }
            atomicAdd(&stats[tid], s);
            atomicAdd(&stats[128 + tid], q);
        }
    }
}

// ---------------- BN finalize: per-channel scale/shift ----------------
__global__ void k_bnfin(const float* __restrict__ stats, const float* __restrict__ gamma,
        const float* __restrict__ beta, float* __restrict__ scsh, float invN) {
    int c = threadIdx.x;
    if (c < CH) {
        float mean = stats[c] * invN;
        float var = stats[CH + c] * invN - mean * mean;   // biased, as in ref
        float sc = gamma[c] * rsqrtf(var + 1e-5f);
        scsh[c] = sc;
        scsh[CH + c] = beta[c] - mean * sc;
    }
}

extern "C" void kernel_launch(void* const* d_in, const int* in_sizes, int n_in,
                              void* d_out, int out_size, void* d_ws, size_t ws_size,
                              hipStream_t stream) {
    const float* x     = (const float*)d_in[0];
    const int*   ei    = (const int*)d_in[1];
    const float* W1    = (const float*)d_in[2];
    const float* b1    = (const float*)d_in[3];
    const float* gamma = (const float*)d_in[4];
    const float* beta  = (const float*)d_in[5];
    const float* W2    = (const float*)d_in[6];
    const float* b2    = (const float*)d_in[7];
    float* out = (float*)d_out;

    const int N = in_sizes[0] / CH;   // 100000
    const int E = in_sizes[1] / 2;    // 1600000
    const int* esrc = ei;
    const int* edst = ei + E;

    char* w = (char*)d_ws;
    auto take = [&](size_t bytes) {
        char* p = w;
        w += (bytes + 255) & ~(size_t)255;
        return p;
    };
    int*      csr    = (int*)take((size_t)E * 4);
    int*      deg    = (int*)take((size_t)N * 4);
    int*      offs   = (int*)take((size_t)(N + 1) * 4);
    int*      cursor = (int*)take((size_t)N * 4);
    int*      bsum   = (int*)take(1024 * 4);
    float*    stats  = (float*)take(256 * 4);
    float*    scsh   = (float*)take(256 * 4);
    uint32_t* xh     = (uint32_t*)take((size_t)N * CH * 2);   // fp16 copy of x
    bool useFp16 = ((size_t)(w - (char*)d_ws) <= ws_size);

    float* h = out;   // d_out doubles as the [N][128] fp32 intermediate

    hipMemsetAsync(deg, 0, (size_t)N * 4, stream);
    hipMemsetAsync(stats, 0, 256 * 4, stream);

    int nb = (N + 1023) / 1024;
    k_hist<<<2048, 256, 0, stream>>>(edst, deg, E);
    k_chunksum<<<nb, 256, 0, stream>>>(deg, bsum, N);
    k_scanwrite<<<nb, 1024, 0, stream>>>(deg, bsum, offs, cursor, N, E);
    {
        const int nPass = 16;
        int rangeSize = (N + nPass - 1) / nPass;   // 6250
        k_scatter<<<2048, 256, 0, stream>>>(esrc, edst, cursor, csr, E, nPass, rangeSize);
    }
    if (useFp16) {
        k_tofp16<<<2048, 256, 0, stream>>>(x, xh, N * CH / 8);
        k_aggregate_h<<<4096, 256, 0, stream>>>(x, (const __half2*)xh, csr, offs, h, N);
    } else {
        k_aggregate<<<4096, 256, 0, stream>>>(x, csr, offs, h, N);
    }
    k_gemm128<<<512, 256, 0, stream>>>(h, W1, b1, h, stats, nullptr, N, 1, 0);
    k_bnfin<<<1, 128, 0, stream>>>(stats, gamma, beta, scsh, 1.0f / (float)N);
    k_gemm128<<<512, 256, 0, stream>>>(h, W2, b2, out, nullptr, scsh, N, 0, 1);
}